// Round 8
// baseline (310.025 us; speedup 1.0000x reference)
//
#include <hip/hip_runtime.h>
#include <math.h>

#define HH 256
#define WW 256
#define HW (HH * WW)
#define TB 10
#define PSTR 260

typedef __attribute__((ext_vector_type(4))) float f32x4;
typedef __attribute__((ext_vector_type(8))) short s16x8;

__device__ __forceinline__ float sp10(float x) {
    float z = 10.0f * x;
    return (fmaxf(z, 0.0f) + log1pf(expf(-fabsf(z)))) * 0.1f;
}

// fp32 -> bf16 RNE
__device__ __forceinline__ unsigned short f2bf(float f) {
    unsigned u = __float_as_uint(f);
    u = u + 0x7FFFu + ((u >> 16) & 1u);
    return (unsigned short)(u >> 16);
}
// split v = hi + lo (both bf16); lo captures next ~8 mantissa bits
__device__ __forceinline__ void bsplit(float v, unsigned short& h, unsigned short& l) {
    h = f2bf(v);
    float hf = __uint_as_float(((unsigned)h) << 16);
    l = f2bf(v - hf);
}
__device__ __forceinline__ unsigned pk(unsigned short a, unsigned short b) {
    return (unsigned)a | ((unsigned)b << 16);
}
__device__ __forceinline__ void sp2(float a, float b, unsigned& uh, unsigned& ul) {
    unsigned short h1, l1, h2, l2;
    bsplit(a, h1, l1); bsplit(b, h2, l2);
    uh = pk(h1, h2); ul = pk(l1, l2);
}

// ---------------------------------------------------------------------------
// Prep: conv1 -> [ci][tap][co32] fp32; conv2 -> [t][co64][ci32] bf16 hi/lo;
// conv3 -> [t][co64][ci64] hi/lo, 54-ch selection (co=(tt-1)*6+g), rest zero.
// ---------------------------------------------------------------------------
__global__ __launch_bounds__(256) void prep_weights(
    const float* __restrict__ w1, const float* __restrict__ w2,
    const float* __restrict__ w3,
    float* __restrict__ wt1,
    unsigned short* __restrict__ wA2h, unsigned short* __restrict__ wA2l,
    unsigned short* __restrict__ wA3h, unsigned short* __restrict__ wA3l)
{
    int idx = blockIdx.x * 256 + threadIdx.x;
    if (idx < 2880) {
        int ci = idx / 288; int rem = idx - ci * 288;
        int tap = rem / 32; int co = rem - tap * 32;
        wt1[idx] = w1[co * 90 + ci * 9 + tap];
    }
    if (idx < 18432) {
        int t = idx / 2048; int rem = idx - t * 2048;
        int co = rem >> 5; int ci = rem & 31;
        unsigned short h, l;
        bsplit(w2[(co * 32 + ci) * 9 + t], h, l);
        wA2h[idx] = h; wA2l[idx] = l;
    }
    if (idx < 36864) {
        int t = idx / 4096; int rem = idx - t * 4096;
        int co = rem >> 6; int ci = rem & 63;
        float v = 0.0f;
        if (co < 54) {
            int tt = co / 6 + 1;
            int g  = co - (tt - 1) * 6;
            v = w3[((g * 10 + tt) * 64 + ci) * 9 + t];
        }
        unsigned short h, l;
        bsplit(v, h, l);
        wA3h[idx] = h; wA3l[idx] = l;
    }
}

// ---------------------------------------------------------------------------
// conv1 (10->32, VALU, 2px/thread). Emits q1 = relu(p1) bf16 hi/lo [h][w][ci32].
// ---------------------------------------------------------------------------
__global__ __launch_bounds__(256, 4) void conv1_k(
    const float* __restrict__ x, const float* __restrict__ wt1,
    unsigned short* __restrict__ q1h, unsigned short* __restrict__ q1l)
{
    __shared__ float tile[10 * 612];
    const int tx = threadIdx.x & 15, ty = threadIdx.x >> 4;
    const int h0 = blockIdx.y * 32, w0 = blockIdx.x * 16;
    const int b = blockIdx.z;
    const float* inb = x + (size_t)b * TB * HW;

    float acc0[32], acc1[32];
#pragma unroll
    for (int c = 0; c < 32; ++c) { acc0[c] = 0.0f; acc1[c] = 0.0f; }

    for (int i = threadIdx.x; i < 10 * 612; i += 256) {
        int ci = i / 612; int r = i - ci * 612;
        int row = r / 18; int col = r - row * 18;
        int gy = h0 + row - 1, gx = w0 + col - 1;
        float v = 0.0f;
        if (gy >= 0 && gy < HH && gx >= 0 && gx < WW)
            v = fmaxf(inb[(size_t)ci * HW + gy * WW + gx], 0.0f);
        tile[i] = v;
    }
    __syncthreads();

    for (int ci = 0; ci < 10; ++ci) {
        const float* tp = &tile[ci * 612 + (2 * ty) * 18 + tx];
        float v[12];
#pragma unroll
        for (int r = 0; r < 4; ++r)
#pragma unroll
            for (int c = 0; c < 3; ++c)
                v[r * 3 + c] = tp[r * 18 + c];
        const float* wp = wt1 + ci * 288;
#pragma unroll
        for (int t = 0; t < 9; ++t) {
            float a0 = v[t], a1 = v[t + 3];
#pragma unroll
            for (int c = 0; c < 32; ++c) {
                float wv = wp[t * 32 + c];
                acc0[c] = fmaf(wv, a0, acc0[c]);
                acc1[c] = fmaf(wv, a1, acc1[c]);
            }
        }
    }

    const int h = h0 + 2 * ty, w = w0 + tx;
    const size_t q1base = (size_t)b * HW * 32;
#pragma unroll
    for (int p = 0; p < 2; ++p) {
        const float* src = p ? acc1 : acc0;
        size_t off = q1base + ((size_t)(h + p) * WW + w) * 32;
#pragma unroll
        for (int g = 0; g < 4; ++g) {
            uint4 Uh, Ul;
            sp2(fmaxf(src[g*8+0],0.f), fmaxf(src[g*8+1],0.f), Uh.x, Ul.x);
            sp2(fmaxf(src[g*8+2],0.f), fmaxf(src[g*8+3],0.f), Uh.y, Ul.y);
            sp2(fmaxf(src[g*8+4],0.f), fmaxf(src[g*8+5],0.f), Uh.z, Ul.z);
            sp2(fmaxf(src[g*8+6],0.f), fmaxf(src[g*8+7],0.f), Uh.w, Ul.w);
            *(uint4*)(q1h + off + g * 8) = Uh;
            *(uint4*)(q1l + off + g * 8) = Ul;
        }
    }
}

// ---------------------------------------------------------------------------
// conv2 (32->64) MFMA split-bf16. ONE staging phase (hi+lo together,
// lds[324][72] shorts = 46.7 KB -> 3 blocks/CU by LDS). A-frags loaded per
// ct-PAIR (16 VGPRs live instead of 32) so arch VGPRs fit under the
// __launch_bounds__(256,3) cap (total <= ~170 incl 64 acc AGPRs -> 3
// waves/SIMD). R6 lesson: cap 128-total forces scratch spill; 170 is safe.
// ---------------------------------------------------------------------------
__global__ __launch_bounds__(256, 3) void conv2_mfma(
    const unsigned short* __restrict__ q1h, const unsigned short* __restrict__ q1l,
    const unsigned short* __restrict__ wA2h, const unsigned short* __restrict__ wA2l,
    unsigned short* __restrict__ q2h, unsigned short* __restrict__ q2l)
{
    __shared__ short lds[324 * 72];   // 46656 B
    const int tid = threadIdx.x;
    const int lane = tid & 63, wave = tid >> 6;
    const int px = lane & 15, quad = lane >> 4;
    const int h0 = blockIdx.y * 16, w0 = blockIdx.x * 16, b = blockIdx.z;

    f32x4 acc[4][4];
#pragma unroll
    for (int r = 0; r < 4; ++r)
#pragma unroll
        for (int ct = 0; ct < 4; ++ct)
            acc[r][ct] = (f32x4){0.f, 0.f, 0.f, 0.f};

    // stage hi+lo halo tile: [pos][hi32|lo32|pad8]
    for (int i = tid; i < 648; i += 256) {
        int plane = (i >= 324) ? 1 : 0;
        int pos = i - plane * 324;
        int row = pos / 18, col = pos - (pos / 18) * 18;
        int gy = h0 + row - 1, gx = w0 + col - 1;
        uint4 v0 = {0,0,0,0}, v1 = v0, v2 = v0, v3 = v0;
        if (gy >= 0 && gy < HH && gx >= 0 && gx < WW) {
            const uint4* gp = (const uint4*)((plane ? q1l : q1h)
                + (size_t)b * HW * 32 + ((size_t)gy * WW + gx) * 32);
            v0 = gp[0]; v1 = gp[1]; v2 = gp[2]; v3 = gp[3];
        }
        uint4* dp = (uint4*)&lds[pos * 72 + plane * 32];
        dp[0] = v0; dp[1] = v1; dp[2] = v2; dp[3] = v3;
    }
    __syncthreads();

#pragma unroll
    for (int t = 0; t < 9; ++t) {
        const int dy = t / 3, dx = t - 3 * (t / 3);
#pragma unroll
        for (int ctp = 0; ctp < 2; ++ctp) {
            const int c0 = ctp * 2;
            int wb0 = (t * 64 + (c0 + 0) * 16 + px) * 32 + quad * 8;
            int wb1 = (t * 64 + (c0 + 1) * 16 + px) * 32 + quad * 8;
            s16x8 ah0 = *(const s16x8*)(wA2h + wb0);
            s16x8 ah1 = *(const s16x8*)(wA2h + wb1);
            s16x8 al0 = *(const s16x8*)(wA2l + wb0);
            s16x8 al1 = *(const s16x8*)(wA2l + wb1);
#pragma unroll
            for (int r = 0; r < 4; ++r) {
                int py = wave * 4 + r;
                const short* bp = &lds[((py + dy) * 18 + (px + dx)) * 72 + quad * 8];
                s16x8 bh = *(const s16x8*)bp;
                s16x8 bl = *(const s16x8*)(bp + 32);
                acc[r][c0+0] = __builtin_amdgcn_mfma_f32_16x16x32_bf16(ah0, bh, acc[r][c0+0], 0, 0, 0);
                acc[r][c0+0] = __builtin_amdgcn_mfma_f32_16x16x32_bf16(al0, bh, acc[r][c0+0], 0, 0, 0);
                acc[r][c0+0] = __builtin_amdgcn_mfma_f32_16x16x32_bf16(ah0, bl, acc[r][c0+0], 0, 0, 0);
                acc[r][c0+1] = __builtin_amdgcn_mfma_f32_16x16x32_bf16(ah1, bh, acc[r][c0+1], 0, 0, 0);
                acc[r][c0+1] = __builtin_amdgcn_mfma_f32_16x16x32_bf16(al1, bh, acc[r][c0+1], 0, 0, 0);
                acc[r][c0+1] = __builtin_amdgcn_mfma_f32_16x16x32_bf16(ah1, bl, acc[r][c0+1], 0, 0, 0);
            }
        }
    }

    // store raw p2 hi/lo: co = ct*16 + quad*4 + reg, col = px
#pragma unroll
    for (int r = 0; r < 4; ++r) {
        int py = wave * 4 + r;
        size_t pix = (size_t)b * HW + (size_t)(h0 + py) * WW + (w0 + px);
#pragma unroll
        for (int ct = 0; ct < 4; ++ct) {
            int co0 = ct * 16 + quad * 4;
            uint2 Uh, Ul;
            sp2(acc[r][ct][0], acc[r][ct][1], Uh.x, Ul.x);
            sp2(acc[r][ct][2], acc[r][ct][3], Uh.y, Ul.y);
            size_t off = pix * 64 + co0;
            *(uint2*)(q2h + off) = Uh;
            *(uint2*)(q2l + off) = Ul;
        }
    }
}

// ---------------------------------------------------------------------------
// conv3 (64 -> 54 pad 64) MFMA. TWO staging phases (ci-halves, hi+lo merged,
// 46.7 KB) + ct-pair A-loads + launch_bounds(256,3) (see conv2 comment) +
// chunked params regroup (reuses the same LDS) + fp32 epilogue.
// ---------------------------------------------------------------------------
__global__ __launch_bounds__(256, 3) void conv3_mfma(
    const unsigned short* __restrict__ q2h, const unsigned short* __restrict__ q2l,
    const unsigned short* __restrict__ wA3h, const unsigned short* __restrict__ wA3l,
    const float* __restrict__ x, const float* __restrict__ pacw,
    const float* __restrict__ pacb, float* __restrict__ out)
{
    __shared__ short lds[324 * 72];   // 46656 B; reused as float for regroup
    float* smemf = (float*)lds;
    const int tid = threadIdx.x;
    const int lane = tid & 63, wave = tid >> 6;
    const int px = lane & 15, quad = lane >> 4;
    const int h0 = blockIdx.y * 16, w0 = blockIdx.x * 16, b = blockIdx.z;

    f32x4 acc[4][4];
#pragma unroll
    for (int r = 0; r < 4; ++r)
#pragma unroll
        for (int ct = 0; ct < 4; ++ct)
            acc[r][ct] = (f32x4){0.f, 0.f, 0.f, 0.f};

#pragma unroll
    for (int half = 0; half < 2; ++half) {
        if (half) __syncthreads();
        for (int i = tid; i < 648; i += 256) {
            int plane = (i >= 324) ? 1 : 0;
            int pos = i - plane * 324;
            int row = pos / 18, col = pos - (pos / 18) * 18;
            int gy = h0 + row - 1, gx = w0 + col - 1;
            uint4 v0 = {0,0,0,0}, v1 = v0, v2 = v0, v3 = v0;
            if (gy >= 0 && gy < HH && gx >= 0 && gx < WW) {
                const uint4* gp = (const uint4*)((plane ? q2l : q2h)
                    + (size_t)b * HW * 64 + ((size_t)gy * WW + gx) * 64 + half * 32);
                v0 = gp[0]; v1 = gp[1]; v2 = gp[2]; v3 = gp[3];
            }
            uint4* dp = (uint4*)&lds[pos * 72 + plane * 32];
            dp[0] = v0; dp[1] = v1; dp[2] = v2; dp[3] = v3;
        }
        __syncthreads();

#pragma unroll
        for (int t = 0; t < 9; ++t) {
            const int dy = t / 3, dx = t - 3 * (t / 3);
#pragma unroll
            for (int ctp = 0; ctp < 2; ++ctp) {
                const int c0 = ctp * 2;
                int wb0 = (t * 64 + (c0 + 0) * 16 + px) * 64 + half * 32 + quad * 8;
                int wb1 = (t * 64 + (c0 + 1) * 16 + px) * 64 + half * 32 + quad * 8;
                s16x8 ah0 = *(const s16x8*)(wA3h + wb0);
                s16x8 ah1 = *(const s16x8*)(wA3h + wb1);
                s16x8 al0 = *(const s16x8*)(wA3l + wb0);
                s16x8 al1 = *(const s16x8*)(wA3l + wb1);
#pragma unroll
                for (int r = 0; r < 4; ++r) {
                    int py = wave * 4 + r;
                    const short* bp = &lds[((py + dy) * 18 + (px + dx)) * 72 + quad * 8];
                    s16x8 bh = *(const s16x8*)bp;
                    s16x8 bl = *(const s16x8*)(bp + 32);
                    acc[r][c0+0] = __builtin_amdgcn_mfma_f32_16x16x32_bf16(ah0, bh, acc[r][c0+0], 0, 0, 0);
                    acc[r][c0+0] = __builtin_amdgcn_mfma_f32_16x16x32_bf16(al0, bh, acc[r][c0+0], 0, 0, 0);
                    acc[r][c0+0] = __builtin_amdgcn_mfma_f32_16x16x32_bf16(ah0, bl, acc[r][c0+0], 0, 0, 0);
                    acc[r][c0+1] = __builtin_amdgcn_mfma_f32_16x16x32_bf16(ah1, bh, acc[r][c0+1], 0, 0, 0);
                    acc[r][c0+1] = __builtin_amdgcn_mfma_f32_16x16x32_bf16(al1, bh, acc[r][c0+1], 0, 0, 0);
                    acc[r][c0+1] = __builtin_amdgcn_mfma_f32_16x16x32_bf16(ah1, bl, acc[r][c0+1], 0, 0, 0);
                }
            }
        }
    }

    // ---- chunked regroup + epilogue ----
    float pw[9];
#pragma unroll
    for (int k = 0; k < 9; ++k) pw[k] = pacw[k];
    const float pbias = pacb[0];
    const int h = h0 + (tid >> 4), w = w0 + (tid & 15);
    const float* xb = x + (size_t)b * TB * HW;
    float* ob = out + (size_t)b * TB * HW;

#pragma unroll
    for (int chunk = 0; chunk < 2; ++chunk) {
        const int lo = chunk * 30, hi = chunk ? 54 : 30;
        __syncthreads();
#pragma unroll
        for (int r = 0; r < 4; ++r) {
            int pfr = (wave * 4 + r) * 16 + px;
#pragma unroll
            for (int ct = 0; ct < 4; ++ct)
#pragma unroll
                for (int g = 0; g < 4; ++g) {
                    int co = ct * 16 + quad * 4 + g;
                    if (co >= lo && co < hi)
                        smemf[(co - lo) * PSTR + pfr] = acc[r][ct][g];
                }
        }
        __syncthreads();

        const int j0 = chunk * 5, j1 = chunk ? 9 : 5;
        for (int j = j0; j < j1; ++j) {
            const int cb = j * 6 - lo;
            float kappa = sp10(smemf[(cb + 0) * PSTR + tid]);
            float m1d   = smemf[(cb + 1) * PSTR + tid];
            float m2d   = smemf[(cb + 2) * PSTR + tid];
            float gamma = sp10(smemf[(cb + 3) * PSTR + tid]);
            float vx    = smemf[(cb + 4) * PSTR + tid];
            float vy    = smemf[(cb + 5) * PSTR + tid];
            float H11 = gamma + vx * vx;
            float H22 = gamma + vy * vy;
            float H12 = vx * vy;
            float iH11 = 1.0f / H11;
            float iH22 = 1.0f / H22;
            float wk[9];
            wk[0] = -0.5f * H12;  wk[1] = -iH22 + m1d;  wk[2] = 0.5f * H12;
            wk[3] = -iH11 - m2d;
            wk[4] = kappa + 2.0f * H11 + 2.0f * H22 + 1.0f;
            wk[5] = -iH11 + m2d;
            wk[6] = 0.5f * H12;   wk[7] = -iH22 - m1d;  wk[8] = -0.5f * H12;

            const float* xc = xb + (size_t)(j + 1) * HW;
            float s = 0.0f;
#pragma unroll
            for (int dy = 0; dy < 3; ++dy)
#pragma unroll
                for (int dx = 0; dx < 3; ++dx) {
                    int gy = h + dy - 1, gx = w + dx - 1;
                    float xv = (gy >= 0 && gy < HH && gx >= 0 && gx < WW)
                                   ? xc[gy * WW + gx] : 0.0f;
                    s = fmaf(pw[dy * 3 + dx] * wk[dy * 3 + dx], xv, s);
                }
            ob[(size_t)j * HW + (size_t)h * WW + w] = s + pbias;
        }
    }
    ob[(size_t)9 * HW + (size_t)h * WW + w] = 0.0f;
}

// ---------------------------------------------------------------------------
extern "C" void kernel_launch(void* const* d_in, const int* in_sizes, int n_in,
                              void* d_out, int out_size, void* d_ws, size_t ws_size,
                              hipStream_t stream)
{
    const float* x    = (const float*)d_in[0];
    const float* w1   = (const float*)d_in[1];
    const float* w2   = (const float*)d_in[2];
    const float* w3   = (const float*)d_in[3];
    const float* pacw = (const float*)d_in[4];
    const float* pacb = (const float*)d_in[5];
    float* out = (float*)d_out;
    char* p = (char*)d_ws;

    float* wt1 = (float*)p;                                       // 11520 B
    unsigned short* wA2h = (unsigned short*)(p + 11520);
    unsigned short* wA2l = (unsigned short*)(p + 11520 + 36864);
    unsigned short* wA3h = (unsigned short*)(p + 11520 + 2 * 36864);
    unsigned short* wA3l = (unsigned short*)(p + 11520 + 2 * 36864 + 73728);
    const size_t woff = 11520 + 2 * 36864 + 2 * 73728;

    prep_weights<<<144, 256, 0, stream>>>(w1, w2, w3, wt1, wA2h, wA2l, wA3h, wA3l);

    const size_t q1sz1 = (size_t)HW * 32 * 2;   // 4 MB
    const size_t q2sz1 = (size_t)HW * 64 * 2;   // 8 MB
    const size_t need_full = woff + 4 * (2 * q1sz1 + 2 * q2sz1);
    dim3 blk(256);

    if (ws_size >= need_full) {
        unsigned short* q1h = (unsigned short*)(p + woff);
        unsigned short* q1l = (unsigned short*)(p + woff + 4 * q1sz1);
        unsigned short* q2h = (unsigned short*)(p + woff + 8 * q1sz1);
        unsigned short* q2l = (unsigned short*)(p + woff + 8 * q1sz1 + 4 * q2sz1);
        conv1_k<<<dim3(16, 8, 4), blk, 0, stream>>>(x, wt1, q1h, q1l);
        conv2_mfma<<<dim3(16, 16, 4), blk, 0, stream>>>(q1h, q1l, wA2h, wA2l, q2h, q2l);
        conv3_mfma<<<dim3(16, 16, 4), blk, 0, stream>>>(q2h, q2l, wA3h, wA3l,
                                                        x, pacw, pacb, out);
    } else {
        unsigned short* q1h = (unsigned short*)(p + woff);
        unsigned short* q1l = (unsigned short*)(p + woff + q1sz1);
        unsigned short* q2h = (unsigned short*)(p + woff + 2 * q1sz1);
        unsigned short* q2l = (unsigned short*)(p + woff + 2 * q1sz1 + q2sz1);
        for (int b = 0; b < 4; ++b) {
            const float* xb = x + (size_t)b * TB * HW;
            float* outb = out + (size_t)b * TB * HW;
            conv1_k<<<dim3(16, 8, 1), blk, 0, stream>>>(xb, wt1, q1h, q1l);
            conv2_mfma<<<dim3(16, 16, 1), blk, 0, stream>>>(q1h, q1l, wA2h, wA2l, q2h, q2l);
            conv3_mfma<<<dim3(16, 16, 1), blk, 0, stream>>>(q2h, q2l, wA3h, wA3l,
                                                            xb, pacw, pacb, outb);
        }
    }
}

// Round 9
// 278.156 us; speedup vs baseline: 1.1146x; 1.1146x over previous
//
#include <hip/hip_runtime.h>
#include <math.h>

#define HH 256
#define WW 256
#define HW (HH * WW)
#define TB 10
#define PSTR 260

typedef __attribute__((ext_vector_type(4))) float f32x4;
typedef __attribute__((ext_vector_type(8))) short s16x8;

__device__ __forceinline__ float sp10(float x) {
    float z = 10.0f * x;
    return (fmaxf(z, 0.0f) + log1pf(expf(-fabsf(z)))) * 0.1f;
}

// fp32 -> bf16 RNE
__device__ __forceinline__ unsigned short f2bf(float f) {
    unsigned u = __float_as_uint(f);
    u = u + 0x7FFFu + ((u >> 16) & 1u);
    return (unsigned short)(u >> 16);
}
// split v = hi + lo (both bf16); lo captures next ~8 mantissa bits
__device__ __forceinline__ void bsplit(float v, unsigned short& h, unsigned short& l) {
    h = f2bf(v);
    float hf = __uint_as_float(((unsigned)h) << 16);
    l = f2bf(v - hf);
}
__device__ __forceinline__ unsigned pk(unsigned short a, unsigned short b) {
    return (unsigned)a | ((unsigned)b << 16);
}
__device__ __forceinline__ void sp2(float a, float b, unsigned& uh, unsigned& ul) {
    unsigned short h1, l1, h2, l2;
    bsplit(a, h1, l1); bsplit(b, h2, l2);
    uh = pk(h1, h2); ul = pk(l1, l2);
}

// ---------------------------------------------------------------------------
// Prep: conv1 -> [ci][tap][co32] fp32; conv2 -> [t][co64][ci32] bf16 hi/lo;
// conv3 -> [t][co64][ci64] hi/lo, 54-ch selection (co=(tt-1)*6+g), rest zero.
// ---------------------------------------------------------------------------
__global__ __launch_bounds__(256) void prep_weights(
    const float* __restrict__ w1, const float* __restrict__ w2,
    const float* __restrict__ w3,
    float* __restrict__ wt1,
    unsigned short* __restrict__ wA2h, unsigned short* __restrict__ wA2l,
    unsigned short* __restrict__ wA3h, unsigned short* __restrict__ wA3l)
{
    int idx = blockIdx.x * 256 + threadIdx.x;
    if (idx < 2880) {
        int ci = idx / 288; int rem = idx - ci * 288;
        int tap = rem / 32; int co = rem - tap * 32;
        wt1[idx] = w1[co * 90 + ci * 9 + tap];
    }
    if (idx < 18432) {
        int t = idx / 2048; int rem = idx - t * 2048;
        int co = rem >> 5; int ci = rem & 31;
        unsigned short h, l;
        bsplit(w2[(co * 32 + ci) * 9 + t], h, l);
        wA2h[idx] = h; wA2l[idx] = l;
    }
    if (idx < 36864) {
        int t = idx / 4096; int rem = idx - t * 4096;
        int co = rem >> 6; int ci = rem & 63;
        float v = 0.0f;
        if (co < 54) {
            int tt = co / 6 + 1;
            int g  = co - (tt - 1) * 6;
            v = w3[((g * 10 + tt) * 64 + ci) * 9 + t];
        }
        unsigned short h, l;
        bsplit(v, h, l);
        wA3h[idx] = h; wA3l[idx] = l;
    }
}

// ---------------------------------------------------------------------------
// conv1 (10->32, VALU, 2px/thread). Emits q1 = relu(p1) bf16 hi/lo [h][w][ci32].
// ---------------------------------------------------------------------------
__global__ __launch_bounds__(256, 4) void conv1_k(
    const float* __restrict__ x, const float* __restrict__ wt1,
    unsigned short* __restrict__ q1h, unsigned short* __restrict__ q1l)
{
    __shared__ float tile[10 * 612];
    const int tx = threadIdx.x & 15, ty = threadIdx.x >> 4;
    const int h0 = blockIdx.y * 32, w0 = blockIdx.x * 16;
    const int b = blockIdx.z;
    const float* inb = x + (size_t)b * TB * HW;

    float acc0[32], acc1[32];
#pragma unroll
    for (int c = 0; c < 32; ++c) { acc0[c] = 0.0f; acc1[c] = 0.0f; }

    for (int i = threadIdx.x; i < 10 * 612; i += 256) {
        int ci = i / 612; int r = i - ci * 612;
        int row = r / 18; int col = r - row * 18;
        int gy = h0 + row - 1, gx = w0 + col - 1;
        float v = 0.0f;
        if (gy >= 0 && gy < HH && gx >= 0 && gx < WW)
            v = fmaxf(inb[(size_t)ci * HW + gy * WW + gx], 0.0f);
        tile[i] = v;
    }
    __syncthreads();

    for (int ci = 0; ci < 10; ++ci) {
        const float* tp = &tile[ci * 612 + (2 * ty) * 18 + tx];
        float v[12];
#pragma unroll
        for (int r = 0; r < 4; ++r)
#pragma unroll
            for (int c = 0; c < 3; ++c)
                v[r * 3 + c] = tp[r * 18 + c];
        const float* wp = wt1 + ci * 288;
#pragma unroll
        for (int t = 0; t < 9; ++t) {
            float a0 = v[t], a1 = v[t + 3];
#pragma unroll
            for (int c = 0; c < 32; ++c) {
                float wv = wp[t * 32 + c];
                acc0[c] = fmaf(wv, a0, acc0[c]);
                acc1[c] = fmaf(wv, a1, acc1[c]);
            }
        }
    }

    const int h = h0 + 2 * ty, w = w0 + tx;
    const size_t q1base = (size_t)b * HW * 32;
#pragma unroll
    for (int p = 0; p < 2; ++p) {
        const float* src = p ? acc1 : acc0;
        size_t off = q1base + ((size_t)(h + p) * WW + w) * 32;
#pragma unroll
        for (int g = 0; g < 4; ++g) {
            uint4 Uh, Ul;
            sp2(fmaxf(src[g*8+0],0.f), fmaxf(src[g*8+1],0.f), Uh.x, Ul.x);
            sp2(fmaxf(src[g*8+2],0.f), fmaxf(src[g*8+3],0.f), Uh.y, Ul.y);
            sp2(fmaxf(src[g*8+4],0.f), fmaxf(src[g*8+5],0.f), Uh.z, Ul.z);
            sp2(fmaxf(src[g*8+6],0.f), fmaxf(src[g*8+7],0.f), Uh.w, Ul.w);
            *(uint4*)(q1h + off + g * 8) = Uh;
            *(uint4*)(q1l + off + g * 8) = Ul;
        }
    }
}

// ---------------------------------------------------------------------------
// conv2 (32->64) MFMA split-bf16, 512 threads / 8 waves on a 16x16 tile.
// Wave = 4 rows x 2 co-tiles -> acc[4][2] = 32 acc regs (R5-R8 lesson: with
// 64 acc/wave any cap tight enough for 3 waves/SIMD spills; halving acc is
// the real knob). launch_bounds(512,4) caps total at 128 (est. need ~107).
// LDS 46.7 KB merged hi/lo staging, single barrier pair.
// ---------------------------------------------------------------------------
__global__ __launch_bounds__(512, 4) void conv2_mfma(
    const unsigned short* __restrict__ q1h, const unsigned short* __restrict__ q1l,
    const unsigned short* __restrict__ wA2h, const unsigned short* __restrict__ wA2l,
    unsigned short* __restrict__ q2h, unsigned short* __restrict__ q2l)
{
    __shared__ short lds[324 * 72];   // 46656 B
    const int tid = threadIdx.x;
    const int lane = tid & 63, wave = tid >> 6;
    const int wq = wave & 3, wc = wave >> 2;
    const int px = lane & 15, quad = lane >> 4;
    const int h0 = blockIdx.y * 16, w0 = blockIdx.x * 16, b = blockIdx.z;

    f32x4 acc[4][2];
#pragma unroll
    for (int r = 0; r < 4; ++r)
#pragma unroll
        for (int c = 0; c < 2; ++c)
            acc[r][c] = (f32x4){0.f, 0.f, 0.f, 0.f};

    // stage hi+lo halo tile: [pos][hi32|lo32|pad8]
    for (int i = tid; i < 648; i += 512) {
        int plane = (i >= 324) ? 1 : 0;
        int pos = i - plane * 324;
        int row = pos / 18, col = pos - (pos / 18) * 18;
        int gy = h0 + row - 1, gx = w0 + col - 1;
        uint4 v0 = {0,0,0,0}, v1 = v0, v2 = v0, v3 = v0;
        if (gy >= 0 && gy < HH && gx >= 0 && gx < WW) {
            const uint4* gp = (const uint4*)((plane ? q1l : q1h)
                + (size_t)b * HW * 32 + ((size_t)gy * WW + gx) * 32);
            v0 = gp[0]; v1 = gp[1]; v2 = gp[2]; v3 = gp[3];
        }
        uint4* dp = (uint4*)&lds[pos * 72 + plane * 32];
        dp[0] = v0; dp[1] = v1; dp[2] = v2; dp[3] = v3;
    }
    __syncthreads();

#pragma unroll
    for (int t = 0; t < 9; ++t) {
        const int dy = t / 3, dx = t - 3 * (t / 3);
        const int ct0 = wc * 2;
        int wb0 = (t * 64 + (ct0 + 0) * 16 + px) * 32 + quad * 8;
        int wb1 = (t * 64 + (ct0 + 1) * 16 + px) * 32 + quad * 8;
        s16x8 ah0 = *(const s16x8*)(wA2h + wb0);
        s16x8 ah1 = *(const s16x8*)(wA2h + wb1);
        s16x8 al0 = *(const s16x8*)(wA2l + wb0);
        s16x8 al1 = *(const s16x8*)(wA2l + wb1);
#pragma unroll
        for (int r = 0; r < 4; ++r) {
            int py = wq * 4 + r;
            const short* bp = &lds[((py + dy) * 18 + (px + dx)) * 72 + quad * 8];
            s16x8 bh = *(const s16x8*)bp;
            s16x8 bl = *(const s16x8*)(bp + 32);
            acc[r][0] = __builtin_amdgcn_mfma_f32_16x16x32_bf16(ah0, bh, acc[r][0], 0, 0, 0);
            acc[r][0] = __builtin_amdgcn_mfma_f32_16x16x32_bf16(al0, bh, acc[r][0], 0, 0, 0);
            acc[r][0] = __builtin_amdgcn_mfma_f32_16x16x32_bf16(ah0, bl, acc[r][0], 0, 0, 0);
            acc[r][1] = __builtin_amdgcn_mfma_f32_16x16x32_bf16(ah1, bh, acc[r][1], 0, 0, 0);
            acc[r][1] = __builtin_amdgcn_mfma_f32_16x16x32_bf16(al1, bh, acc[r][1], 0, 0, 0);
            acc[r][1] = __builtin_amdgcn_mfma_f32_16x16x32_bf16(ah1, bl, acc[r][1], 0, 0, 0);
        }
    }

    // store raw p2 hi/lo: co = ct*16 + quad*4 + reg, col = px
#pragma unroll
    for (int r = 0; r < 4; ++r) {
        int py = wq * 4 + r;
        size_t pix = (size_t)b * HW + (size_t)(h0 + py) * WW + (w0 + px);
#pragma unroll
        for (int c = 0; c < 2; ++c) {
            int co0 = (wc * 2 + c) * 16 + quad * 4;
            uint2 Uh, Ul;
            sp2(acc[r][c][0], acc[r][c][1], Uh.x, Ul.x);
            sp2(acc[r][c][2], acc[r][c][3], Uh.y, Ul.y);
            size_t off = pix * 64 + co0;
            *(uint2*)(q2h + off) = Uh;
            *(uint2*)(q2l + off) = Ul;
        }
    }
}

// ---------------------------------------------------------------------------
// conv3 (64 -> 54 pad 64) MFMA, 512 threads / 8 waves, acc[4][2]=32 regs.
// Two staging phases (ci-halves, hi+lo merged, 46.7 KB) + chunked params
// regroup + fp32 epilogue split across thread-halves.
// ---------------------------------------------------------------------------
__global__ __launch_bounds__(512, 4) void conv3_mfma(
    const unsigned short* __restrict__ q2h, const unsigned short* __restrict__ q2l,
    const unsigned short* __restrict__ wA3h, const unsigned short* __restrict__ wA3l,
    const float* __restrict__ x, const float* __restrict__ pacw,
    const float* __restrict__ pacb, float* __restrict__ out)
{
    __shared__ short lds[324 * 72];   // 46656 B; reused as float for regroup
    float* smemf = (float*)lds;
    const int tid = threadIdx.x;
    const int lane = tid & 63, wave = tid >> 6;
    const int wq = wave & 3, wc = wave >> 2;
    const int px = lane & 15, quad = lane >> 4;
    const int h0 = blockIdx.y * 16, w0 = blockIdx.x * 16, b = blockIdx.z;

    f32x4 acc[4][2];
#pragma unroll
    for (int r = 0; r < 4; ++r)
#pragma unroll
        for (int c = 0; c < 2; ++c)
            acc[r][c] = (f32x4){0.f, 0.f, 0.f, 0.f};

#pragma unroll
    for (int half = 0; half < 2; ++half) {
        if (half) __syncthreads();
        for (int i = tid; i < 648; i += 512) {
            int plane = (i >= 324) ? 1 : 0;
            int pos = i - plane * 324;
            int row = pos / 18, col = pos - (pos / 18) * 18;
            int gy = h0 + row - 1, gx = w0 + col - 1;
            uint4 v0 = {0,0,0,0}, v1 = v0, v2 = v0, v3 = v0;
            if (gy >= 0 && gy < HH && gx >= 0 && gx < WW) {
                const uint4* gp = (const uint4*)((plane ? q2l : q2h)
                    + (size_t)b * HW * 64 + ((size_t)gy * WW + gx) * 64 + half * 32);
                v0 = gp[0]; v1 = gp[1]; v2 = gp[2]; v3 = gp[3];
            }
            uint4* dp = (uint4*)&lds[pos * 72 + plane * 32];
            dp[0] = v0; dp[1] = v1; dp[2] = v2; dp[3] = v3;
        }
        __syncthreads();

#pragma unroll
        for (int t = 0; t < 9; ++t) {
            const int dy = t / 3, dx = t - 3 * (t / 3);
            const int ct0 = wc * 2;
            int wb0 = (t * 64 + (ct0 + 0) * 16 + px) * 64 + half * 32 + quad * 8;
            int wb1 = (t * 64 + (ct0 + 1) * 16 + px) * 64 + half * 32 + quad * 8;
            s16x8 ah0 = *(const s16x8*)(wA3h + wb0);
            s16x8 ah1 = *(const s16x8*)(wA3h + wb1);
            s16x8 al0 = *(const s16x8*)(wA3l + wb0);
            s16x8 al1 = *(const s16x8*)(wA3l + wb1);
#pragma unroll
            for (int r = 0; r < 4; ++r) {
                int py = wq * 4 + r;
                const short* bp = &lds[((py + dy) * 18 + (px + dx)) * 72 + quad * 8];
                s16x8 bh = *(const s16x8*)bp;
                s16x8 bl = *(const s16x8*)(bp + 32);
                acc[r][0] = __builtin_amdgcn_mfma_f32_16x16x32_bf16(ah0, bh, acc[r][0], 0, 0, 0);
                acc[r][0] = __builtin_amdgcn_mfma_f32_16x16x32_bf16(al0, bh, acc[r][0], 0, 0, 0);
                acc[r][0] = __builtin_amdgcn_mfma_f32_16x16x32_bf16(ah0, bl, acc[r][0], 0, 0, 0);
                acc[r][1] = __builtin_amdgcn_mfma_f32_16x16x32_bf16(ah1, bh, acc[r][1], 0, 0, 0);
                acc[r][1] = __builtin_amdgcn_mfma_f32_16x16x32_bf16(al1, bh, acc[r][1], 0, 0, 0);
                acc[r][1] = __builtin_amdgcn_mfma_f32_16x16x32_bf16(ah1, bl, acc[r][1], 0, 0, 0);
            }
        }
    }

    // ---- chunked regroup + epilogue ----
    float pw[9];
#pragma unroll
    for (int k = 0; k < 9; ++k) pw[k] = pacw[k];
    const float pbias = pacb[0];
    const int grp = tid >> 8;         // 0 or 1: epilogue j-split
    const int pidx = tid & 255;       // pixel within tile
    const int h = h0 + (pidx >> 4), w = w0 + (pidx & 15);
    const float* xb = x + (size_t)b * TB * HW;
    float* ob = out + (size_t)b * TB * HW;

#pragma unroll
    for (int chunk = 0; chunk < 2; ++chunk) {
        const int lo = chunk * 30, hi = chunk ? 54 : 30;
        __syncthreads();
#pragma unroll
        for (int r = 0; r < 4; ++r) {
            int pfr = (wq * 4 + r) * 16 + px;
#pragma unroll
            for (int c = 0; c < 2; ++c)
#pragma unroll
                for (int g = 0; g < 4; ++g) {
                    int co = (wc * 2 + c) * 16 + quad * 4 + g;
                    if (co >= lo && co < hi)
                        smemf[(co - lo) * PSTR + pfr] = acc[r][c][g];
                }
        }
        __syncthreads();

        // chunk0: j 0-4 -> grp0 {0,1,2} grp1 {3,4}; chunk1: j 5-8 -> {5,6} {7,8}
        const int j0 = chunk ? (grp ? 7 : 5) : (grp ? 3 : 0);
        const int j1 = chunk ? (grp ? 9 : 7) : (grp ? 5 : 3);
        for (int j = j0; j < j1; ++j) {
            const int cb = j * 6 - lo;
            float kappa = sp10(smemf[(cb + 0) * PSTR + pidx]);
            float m1d   = smemf[(cb + 1) * PSTR + pidx];
            float m2d   = smemf[(cb + 2) * PSTR + pidx];
            float gamma = sp10(smemf[(cb + 3) * PSTR + pidx]);
            float vx    = smemf[(cb + 4) * PSTR + pidx];
            float vy    = smemf[(cb + 5) * PSTR + pidx];
            float H11 = gamma + vx * vx;
            float H22 = gamma + vy * vy;
            float H12 = vx * vy;
            float iH11 = 1.0f / H11;
            float iH22 = 1.0f / H22;
            float wk[9];
            wk[0] = -0.5f * H12;  wk[1] = -iH22 + m1d;  wk[2] = 0.5f * H12;
            wk[3] = -iH11 - m2d;
            wk[4] = kappa + 2.0f * H11 + 2.0f * H22 + 1.0f;
            wk[5] = -iH11 + m2d;
            wk[6] = 0.5f * H12;   wk[7] = -iH22 - m1d;  wk[8] = -0.5f * H12;

            const float* xc = xb + (size_t)(j + 1) * HW;
            float s = 0.0f;
#pragma unroll
            for (int dy = 0; dy < 3; ++dy)
#pragma unroll
                for (int dx = 0; dx < 3; ++dx) {
                    int gy = h + dy - 1, gx = w + dx - 1;
                    float xv = (gy >= 0 && gy < HH && gx >= 0 && gx < WW)
                                   ? xc[gy * WW + gx] : 0.0f;
                    s = fmaf(pw[dy * 3 + dx] * wk[dy * 3 + dx], xv, s);
                }
            ob[(size_t)j * HW + (size_t)h * WW + w] = s + pbias;
        }
    }
    if (grp == 0)
        ob[(size_t)9 * HW + (size_t)h * WW + w] = 0.0f;
}

// ---------------------------------------------------------------------------
extern "C" void kernel_launch(void* const* d_in, const int* in_sizes, int n_in,
                              void* d_out, int out_size, void* d_ws, size_t ws_size,
                              hipStream_t stream)
{
    const float* x    = (const float*)d_in[0];
    const float* w1   = (const float*)d_in[1];
    const float* w2   = (const float*)d_in[2];
    const float* w3   = (const float*)d_in[3];
    const float* pacw = (const float*)d_in[4];
    const float* pacb = (const float*)d_in[5];
    float* out = (float*)d_out;
    char* p = (char*)d_ws;

    float* wt1 = (float*)p;                                       // 11520 B
    unsigned short* wA2h = (unsigned short*)(p + 11520);
    unsigned short* wA2l = (unsigned short*)(p + 11520 + 36864);
    unsigned short* wA3h = (unsigned short*)(p + 11520 + 2 * 36864);
    unsigned short* wA3l = (unsigned short*)(p + 11520 + 2 * 36864 + 73728);
    const size_t woff = 11520 + 2 * 36864 + 2 * 73728;

    prep_weights<<<144, 256, 0, stream>>>(w1, w2, w3, wt1, wA2h, wA2l, wA3h, wA3l);

    const size_t q1sz1 = (size_t)HW * 32 * 2;   // 4 MB
    const size_t q2sz1 = (size_t)HW * 64 * 2;   // 8 MB
    const size_t need_full = woff + 4 * (2 * q1sz1 + 2 * q2sz1);

    if (ws_size >= need_full) {
        unsigned short* q1h = (unsigned short*)(p + woff);
        unsigned short* q1l = (unsigned short*)(p + woff + 4 * q1sz1);
        unsigned short* q2h = (unsigned short*)(p + woff + 8 * q1sz1);
        unsigned short* q2l = (unsigned short*)(p + woff + 8 * q1sz1 + 4 * q2sz1);
        conv1_k<<<dim3(16, 8, 4), dim3(256), 0, stream>>>(x, wt1, q1h, q1l);
        conv2_mfma<<<dim3(16, 16, 4), dim3(512), 0, stream>>>(q1h, q1l, wA2h, wA2l, q2h, q2l);
        conv3_mfma<<<dim3(16, 16, 4), dim3(512), 0, stream>>>(q2h, q2l, wA3h, wA3l,
                                                              x, pacw, pacb, out);
    } else {
        unsigned short* q1h = (unsigned short*)(p + woff);
        unsigned short* q1l = (unsigned short*)(p + woff + q1sz1);
        unsigned short* q2h = (unsigned short*)(p + woff + 2 * q1sz1);
        unsigned short* q2l = (unsigned short*)(p + woff + 2 * q1sz1 + q2sz1);
        for (int b = 0; b < 4; ++b) {
            const float* xb = x + (size_t)b * TB * HW;
            float* outb = out + (size_t)b * TB * HW;
            conv1_k<<<dim3(16, 8, 1), dim3(256), 0, stream>>>(xb, wt1, q1h, q1l);
            conv2_mfma<<<dim3(16, 16, 1), dim3(512), 0, stream>>>(q1h, q1l, wA2h, wA2l, q2h, q2l);
            conv3_mfma<<<dim3(16, 16, 1), dim3(512), 0, stream>>>(q2h, q2l, wA3h, wA3l,
                                                                  xb, pacw, pacb, outb);
        }
    }
}

// Round 10
// 265.628 us; speedup vs baseline: 1.1671x; 1.0472x over previous
//
#include <hip/hip_runtime.h>
#include <math.h>

#define HH 256
#define WW 256
#define HW (HH * WW)
#define TB 10
#define PSTR 260

typedef __attribute__((ext_vector_type(4))) float f32x4;
typedef __attribute__((ext_vector_type(8))) short s16x8;

__device__ __forceinline__ float sp10(float x) {
    float z = 10.0f * x;
    return (fmaxf(z, 0.0f) + log1pf(expf(-fabsf(z)))) * 0.1f;
}

// fp32 -> bf16 RNE
__device__ __forceinline__ unsigned short f2bf(float f) {
    unsigned u = __float_as_uint(f);
    u = u + 0x7FFFu + ((u >> 16) & 1u);
    return (unsigned short)(u >> 16);
}
__device__ __forceinline__ void bsplit(float v, unsigned short& h, unsigned short& l) {
    h = f2bf(v);
    float hf = __uint_as_float(((unsigned)h) << 16);
    l = f2bf(v - hf);
}
__device__ __forceinline__ unsigned pk(unsigned short a, unsigned short b) {
    return (unsigned)a | ((unsigned)b << 16);
}
__device__ __forceinline__ void sp2(float a, float b, unsigned& uh, unsigned& ul) {
    unsigned short h1, l1, h2, l2;
    bsplit(a, h1, l1); bsplit(b, h2, l2);
    uh = pk(h1, h2); ul = pk(l1, l2);
}

// NB pow2 so blockIdx.z decomposition stays scalar (no s_div on gfx950!)
template <int NB> __device__ __forceinline__ int log2nb() {
    static_assert(NB == 1 || NB == 2 || NB == 4, "NB pow2");
    return NB == 4 ? 2 : (NB == 2 ? 1 : 0);
}

// ---------------------------------------------------------------------------
// Prep: conv1 -> [ci][tap][co32] fp32; conv2 -> [t][co64][ci32] bf16 hi/lo;
// conv3 -> [t][co64][ci64] hi/lo, 54-ch selection (co=(tt-1)*6+g), rest zero.
// ---------------------------------------------------------------------------
__global__ __launch_bounds__(256) void prep_weights(
    const float* __restrict__ w1, const float* __restrict__ w2,
    const float* __restrict__ w3,
    float* __restrict__ wt1,
    unsigned short* __restrict__ wA2h, unsigned short* __restrict__ wA2l,
    unsigned short* __restrict__ wA3h, unsigned short* __restrict__ wA3l)
{
    int idx = blockIdx.x * 256 + threadIdx.x;
    if (idx < 2880) {
        int ci = idx / 288; int rem = idx - ci * 288;
        int tap = rem / 32; int co = rem - tap * 32;
        wt1[idx] = w1[co * 90 + ci * 9 + tap];
    }
    if (idx < 18432) {
        int t = idx / 2048; int rem = idx - t * 2048;
        int co = rem >> 5; int ci = rem & 31;
        unsigned short h, l;
        bsplit(w2[(co * 32 + ci) * 9 + t], h, l);
        wA2h[idx] = h; wA2l[idx] = l;
    }
    if (idx < 36864) {
        int t = idx / 4096; int rem = idx - t * 4096;
        int co = rem >> 6; int ci = rem & 63;
        float v = 0.0f;
        if (co < 54) {
            int tt = co / 6 + 1;
            int g  = co - (tt - 1) * 6;
            v = w3[((g * 10 + tt) * 64 + ci) * 9 + t];
        }
        unsigned short h, l;
        bsplit(v, h, l);
        wA3h[idx] = h; wA3l[idx] = l;
    }
}

// ---------------------------------------------------------------------------
// conv1 (10->32, VALU, 2px/thread). Emits q1 = relu(p1) bf16 hi/lo [h][w][ci32].
// ---------------------------------------------------------------------------
__global__ __launch_bounds__(256, 4) void conv1_k(
    const float* __restrict__ x, const float* __restrict__ wt1,
    unsigned short* __restrict__ q1h, unsigned short* __restrict__ q1l)
{
    __shared__ float tile[10 * 612];
    const int tx = threadIdx.x & 15, ty = threadIdx.x >> 4;
    const int h0 = blockIdx.y * 32, w0 = blockIdx.x * 16;
    const int b = blockIdx.z;
    const float* inb = x + (size_t)b * TB * HW;

    float acc0[32], acc1[32];
#pragma unroll
    for (int c = 0; c < 32; ++c) { acc0[c] = 0.0f; acc1[c] = 0.0f; }

    for (int i = threadIdx.x; i < 10 * 612; i += 256) {
        int ci = i / 612; int r = i - ci * 612;
        int row = r / 18; int col = r - row * 18;
        int gy = h0 + row - 1, gx = w0 + col - 1;
        float v = 0.0f;
        if (gy >= 0 && gy < HH && gx >= 0 && gx < WW)
            v = fmaxf(inb[(size_t)ci * HW + gy * WW + gx], 0.0f);
        tile[i] = v;
    }
    __syncthreads();

    for (int ci = 0; ci < 10; ++ci) {
        const float* tp = &tile[ci * 612 + (2 * ty) * 18 + tx];
        float v[12];
#pragma unroll
        for (int r = 0; r < 4; ++r)
#pragma unroll
            for (int c = 0; c < 3; ++c)
                v[r * 3 + c] = tp[r * 18 + c];
        const float* wp = wt1 + ci * 288;
#pragma unroll
        for (int t = 0; t < 9; ++t) {
            float a0 = v[t], a1 = v[t + 3];
#pragma unroll
            for (int c = 0; c < 32; ++c) {
                float wv = wp[t * 32 + c];
                acc0[c] = fmaf(wv, a0, acc0[c]);
                acc1[c] = fmaf(wv, a1, acc1[c]);
            }
        }
    }

    const int h = h0 + 2 * ty, w = w0 + tx;
    const size_t q1base = (size_t)b * HW * 32;
#pragma unroll
    for (int p = 0; p < 2; ++p) {
        const float* src = p ? acc1 : acc0;
        size_t off = q1base + ((size_t)(h + p) * WW + w) * 32;
#pragma unroll
        for (int g = 0; g < 4; ++g) {
            uint4 Uh, Ul;
            sp2(fmaxf(src[g*8+0],0.f), fmaxf(src[g*8+1],0.f), Uh.x, Ul.x);
            sp2(fmaxf(src[g*8+2],0.f), fmaxf(src[g*8+3],0.f), Uh.y, Ul.y);
            sp2(fmaxf(src[g*8+4],0.f), fmaxf(src[g*8+5],0.f), Uh.z, Ul.z);
            sp2(fmaxf(src[g*8+6],0.f), fmaxf(src[g*8+7],0.f), Uh.w, Ul.w);
            *(uint4*)(q1h + off + g * 8) = Uh;
            *(uint4*)(q1l + off + g * 8) = Ul;
        }
    }
}

// ---------------------------------------------------------------------------
// conv2 (32->64) MFMA split-bf16, CO-SPLIT across grid.z (32 co per block):
// acc[4][2]=32 AGPR + A-frags 32 VGPR -> natural total ~140 regs, aiming for
// 3 waves/SIMD WITHOUT launch-bounds caps (R6/R8/R9: every cap -> spill).
// Champion staging (merged hi/lo, 46.7 KB, single barrier pair).
// ---------------------------------------------------------------------------
template <int NB>
__global__ __launch_bounds__(256) void conv2_mfma(
    const unsigned short* __restrict__ q1h, const unsigned short* __restrict__ q1l,
    const unsigned short* __restrict__ wA2h, const unsigned short* __restrict__ wA2l,
    unsigned short* __restrict__ q2h, unsigned short* __restrict__ q2l)
{
    __shared__ short lds[324 * 72];   // 46656 B
    const int tid = threadIdx.x;
    const int lane = tid & 63, wave = tid >> 6;
    const int px = lane & 15, quad = lane >> 4;
    const int z = blockIdx.z;
    const int b = z & (NB - 1);
    const int cohalf = z >> log2nb<NB>();   // 0/1 -> co 0..31 / 32..63
    const int h0 = blockIdx.y * 16, w0 = blockIdx.x * 16;

    f32x4 acc[4][2];
#pragma unroll
    for (int r = 0; r < 4; ++r)
#pragma unroll
        for (int c = 0; c < 2; ++c)
            acc[r][c] = (f32x4){0.f, 0.f, 0.f, 0.f};

    // stage hi+lo halo tile: [pos][hi32|lo32|pad8]
    for (int i = tid; i < 648; i += 256) {
        int plane = (i >= 324) ? 1 : 0;
        int pos = i - plane * 324;
        int row = pos / 18, col = pos - (pos / 18) * 18;
        int gy = h0 + row - 1, gx = w0 + col - 1;
        uint4 v0 = {0,0,0,0}, v1 = v0, v2 = v0, v3 = v0;
        if (gy >= 0 && gy < HH && gx >= 0 && gx < WW) {
            const uint4* gp = (const uint4*)((plane ? q1l : q1h)
                + (size_t)b * HW * 32 + ((size_t)gy * WW + gx) * 32);
            v0 = gp[0]; v1 = gp[1]; v2 = gp[2]; v3 = gp[3];
        }
        uint4* dp = (uint4*)&lds[pos * 72 + plane * 32];
        dp[0] = v0; dp[1] = v1; dp[2] = v2; dp[3] = v3;
    }
    __syncthreads();

#pragma unroll
    for (int t = 0; t < 9; ++t) {
        const int dy = t / 3, dx = t - 3 * (t / 3);
        s16x8 ah[2], al[2];
#pragma unroll
        for (int ct = 0; ct < 2; ++ct) {
            int wb = (t * 64 + cohalf * 32 + ct * 16 + px) * 32 + quad * 8;
            ah[ct] = *(const s16x8*)(wA2h + wb);
            al[ct] = *(const s16x8*)(wA2l + wb);
        }
#pragma unroll
        for (int r = 0; r < 4; ++r) {
            int py = wave * 4 + r;
            const short* bp = &lds[((py + dy) * 18 + (px + dx)) * 72 + quad * 8];
            s16x8 bh = *(const s16x8*)bp;
            s16x8 bl = *(const s16x8*)(bp + 32);
#pragma unroll
            for (int ct = 0; ct < 2; ++ct) {
                acc[r][ct] = __builtin_amdgcn_mfma_f32_16x16x32_bf16(ah[ct], bh, acc[r][ct], 0, 0, 0);
                acc[r][ct] = __builtin_amdgcn_mfma_f32_16x16x32_bf16(al[ct], bh, acc[r][ct], 0, 0, 0);
                acc[r][ct] = __builtin_amdgcn_mfma_f32_16x16x32_bf16(ah[ct], bl, acc[r][ct], 0, 0, 0);
            }
        }
    }

    // store raw p2 hi/lo: co = cohalf*32 + ct*16 + quad*4 + reg
#pragma unroll
    for (int r = 0; r < 4; ++r) {
        int py = wave * 4 + r;
        size_t pix = (size_t)b * HW + (size_t)(h0 + py) * WW + (w0 + px);
#pragma unroll
        for (int ct = 0; ct < 2; ++ct) {
            int co0 = cohalf * 32 + ct * 16 + quad * 4;
            uint2 Uh, Ul;
            sp2(acc[r][ct][0], acc[r][ct][1], Uh.x, Ul.x);
            sp2(acc[r][ct][2], acc[r][ct][3], Uh.y, Ul.y);
            size_t off = pix * 64 + co0;
            *(uint2*)(q2h + off) = Uh;
            *(uint2*)(q2l + off) = Ul;
        }
    }
}

// ---------------------------------------------------------------------------
// conv3 (64 -> 54 pad 64) MFMA, CO-SPLIT: half0 co 0..31 -> j 0..4,
// half1 co 24..55 -> j 4..8 (j4 written bitwise-identically by both; R2
// overlap trick). acc[4][2]; two ci-half staging phases (champion pattern);
// regroup buffer (30 x PSTR fp32 = 31.2 KB) reuses staging LDS -> 46.7 KB.
// No launch-bounds min (caps spill: R6/R8/R9).
// ---------------------------------------------------------------------------
template <int NB>
__global__ __launch_bounds__(256) void conv3_mfma(
    const unsigned short* __restrict__ q2h, const unsigned short* __restrict__ q2l,
    const unsigned short* __restrict__ wA3h, const unsigned short* __restrict__ wA3l,
    const float* __restrict__ x, const float* __restrict__ pacw,
    const float* __restrict__ pacb, float* __restrict__ out)
{
    __shared__ short lds[324 * 72];   // 46656 B; reused as float regroup
    float* smemf = (float*)lds;
    const int tid = threadIdx.x;
    const int lane = tid & 63, wave = tid >> 6;
    const int px = lane & 15, quad = lane >> 4;
    const int z = blockIdx.z;
    const int b = z & (NB - 1);
    const int cohalf = z >> log2nb<NB>();
    const int base = cohalf * 24;          // co offset into wA3 (0 or 24)
    const int h0 = blockIdx.y * 16, w0 = blockIdx.x * 16;

    f32x4 acc[4][2];
#pragma unroll
    for (int r = 0; r < 4; ++r)
#pragma unroll
        for (int c = 0; c < 2; ++c)
            acc[r][c] = (f32x4){0.f, 0.f, 0.f, 0.f};

#pragma unroll
    for (int khalf = 0; khalf < 2; ++khalf) {
        if (khalf) __syncthreads();
        for (int i = tid; i < 648; i += 256) {
            int plane = (i >= 324) ? 1 : 0;
            int pos = i - plane * 324;
            int row = pos / 18, col = pos - (pos / 18) * 18;
            int gy = h0 + row - 1, gx = w0 + col - 1;
            uint4 v0 = {0,0,0,0}, v1 = v0, v2 = v0, v3 = v0;
            if (gy >= 0 && gy < HH && gx >= 0 && gx < WW) {
                const uint4* gp = (const uint4*)((plane ? q2l : q2h)
                    + (size_t)b * HW * 64 + ((size_t)gy * WW + gx) * 64 + khalf * 32);
                v0 = gp[0]; v1 = gp[1]; v2 = gp[2]; v3 = gp[3];
            }
            uint4* dp = (uint4*)&lds[pos * 72 + plane * 32];
            dp[0] = v0; dp[1] = v1; dp[2] = v2; dp[3] = v3;
        }
        __syncthreads();

#pragma unroll
        for (int t = 0; t < 9; ++t) {
            const int dy = t / 3, dx = t - 3 * (t / 3);
            s16x8 ah[2], al[2];
#pragma unroll
            for (int ct = 0; ct < 2; ++ct) {
                int wb = (t * 64 + base + ct * 16 + px) * 64 + khalf * 32 + quad * 8;
                ah[ct] = *(const s16x8*)(wA3h + wb);
                al[ct] = *(const s16x8*)(wA3l + wb);
            }
#pragma unroll
            for (int r = 0; r < 4; ++r) {
                int py = wave * 4 + r;
                const short* bp = &lds[((py + dy) * 18 + (px + dx)) * 72 + quad * 8];
                s16x8 bh = *(const s16x8*)bp;
                s16x8 bl = *(const s16x8*)(bp + 32);
#pragma unroll
                for (int ct = 0; ct < 2; ++ct) {
                    acc[r][ct] = __builtin_amdgcn_mfma_f32_16x16x32_bf16(ah[ct], bh, acc[r][ct], 0, 0, 0);
                    acc[r][ct] = __builtin_amdgcn_mfma_f32_16x16x32_bf16(al[ct], bh, acc[r][ct], 0, 0, 0);
                    acc[r][ct] = __builtin_amdgcn_mfma_f32_16x16x32_bf16(ah[ct], bl, acc[r][ct], 0, 0, 0);
                }
            }
        }
    }

    // ---- regroup (slots 0..29 = this half's 5 j-groups) + epilogue ----
    __syncthreads();
#pragma unroll
    for (int r = 0; r < 4; ++r) {
        int pfr = (wave * 4 + r) * 16 + px;
#pragma unroll
        for (int ct = 0; ct < 2; ++ct)
#pragma unroll
            for (int g = 0; g < 4; ++g) {
                int slot = ct * 16 + quad * 4 + g;   // local co (global = base+slot)
                if (slot < 30)
                    smemf[slot * PSTR + pfr] = acc[r][ct][g];
            }
    }
    __syncthreads();

    float pw[9];
#pragma unroll
    for (int k = 0; k < 9; ++k) pw[k] = pacw[k];
    const float pbias = pacb[0];
    const int h = h0 + (tid >> 4), w = w0 + (tid & 15);
    const float* xb = x + (size_t)b * TB * HW;
    float* ob = out + (size_t)b * TB * HW;

#pragma unroll
    for (int k = 0; k < 5; ++k) {
        const int j = cohalf * 4 + k;     // half0: j0..4, half1: j4..8
        const int cb = k * 6;
        float kappa = sp10(smemf[(cb + 0) * PSTR + tid]);
        float m1d   = smemf[(cb + 1) * PSTR + tid];
        float m2d   = smemf[(cb + 2) * PSTR + tid];
        float gamma = sp10(smemf[(cb + 3) * PSTR + tid]);
        float vx    = smemf[(cb + 4) * PSTR + tid];
        float vy    = smemf[(cb + 5) * PSTR + tid];
        float H11 = gamma + vx * vx;
        float H22 = gamma + vy * vy;
        float H12 = vx * vy;
        float iH11 = 1.0f / H11;
        float iH22 = 1.0f / H22;
        float wk[9];
        wk[0] = -0.5f * H12;  wk[1] = -iH22 + m1d;  wk[2] = 0.5f * H12;
        wk[3] = -iH11 - m2d;
        wk[4] = kappa + 2.0f * H11 + 2.0f * H22 + 1.0f;
        wk[5] = -iH11 + m2d;
        wk[6] = 0.5f * H12;   wk[7] = -iH22 - m1d;  wk[8] = -0.5f * H12;

        const float* xc = xb + (size_t)(j + 1) * HW;
        float s = 0.0f;
#pragma unroll
        for (int dy = 0; dy < 3; ++dy)
#pragma unroll
            for (int dx = 0; dx < 3; ++dx) {
                int gy = h + dy - 1, gx = w + dx - 1;
                float xv = (gy >= 0 && gy < HH && gx >= 0 && gx < WW)
                               ? xc[gy * WW + gx] : 0.0f;
                s = fmaf(pw[dy * 3 + dx] * wk[dy * 3 + dx], xv, s);
            }
        ob[(size_t)j * HW + (size_t)h * WW + w] = s + pbias;
    }
    if (cohalf)
        ob[(size_t)9 * HW + (size_t)h * WW + w] = 0.0f;
}

// ---------------------------------------------------------------------------
extern "C" void kernel_launch(void* const* d_in, const int* in_sizes, int n_in,
                              void* d_out, int out_size, void* d_ws, size_t ws_size,
                              hipStream_t stream)
{
    const float* x    = (const float*)d_in[0];
    const float* w1   = (const float*)d_in[1];
    const float* w2   = (const float*)d_in[2];
    const float* w3   = (const float*)d_in[3];
    const float* pacw = (const float*)d_in[4];
    const float* pacb = (const float*)d_in[5];
    float* out = (float*)d_out;
    char* p = (char*)d_ws;

    float* wt1 = (float*)p;                                       // 11520 B
    unsigned short* wA2h = (unsigned short*)(p + 11520);
    unsigned short* wA2l = (unsigned short*)(p + 11520 + 36864);
    unsigned short* wA3h = (unsigned short*)(p + 11520 + 2 * 36864);
    unsigned short* wA3l = (unsigned short*)(p + 11520 + 2 * 36864 + 73728);
    const size_t woff = 11520 + 2 * 36864 + 2 * 73728;

    prep_weights<<<144, 256, 0, stream>>>(w1, w2, w3, wt1, wA2h, wA2l, wA3h, wA3l);

    const size_t q1sz1 = (size_t)HW * 32 * 2;   // 4 MB
    const size_t q2sz1 = (size_t)HW * 64 * 2;   // 8 MB
    const size_t need_full = woff + 4 * (2 * q1sz1 + 2 * q2sz1);
    dim3 blk(256);

    if (ws_size >= need_full) {
        unsigned short* q1h = (unsigned short*)(p + woff);
        unsigned short* q1l = (unsigned short*)(p + woff + 4 * q1sz1);
        unsigned short* q2h = (unsigned short*)(p + woff + 8 * q1sz1);
        unsigned short* q2l = (unsigned short*)(p + woff + 8 * q1sz1 + 4 * q2sz1);
        conv1_k<<<dim3(16, 8, 4), blk, 0, stream>>>(x, wt1, q1h, q1l);
        conv2_mfma<4><<<dim3(16, 16, 8), blk, 0, stream>>>(q1h, q1l, wA2h, wA2l, q2h, q2l);
        conv3_mfma<4><<<dim3(16, 16, 8), blk, 0, stream>>>(q2h, q2l, wA3h, wA3l,
                                                           x, pacw, pacb, out);
    } else {
        unsigned short* q1h = (unsigned short*)(p + woff);
        unsigned short* q1l = (unsigned short*)(p + woff + q1sz1);
        unsigned short* q2h = (unsigned short*)(p + woff + 2 * q1sz1);
        unsigned short* q2l = (unsigned short*)(p + woff + 2 * q1sz1 + q2sz1);
        for (int b = 0; b < 4; ++b) {
            const float* xb = x + (size_t)b * TB * HW;
            float* outb = out + (size_t)b * TB * HW;
            conv1_k<<<dim3(16, 8, 1), blk, 0, stream>>>(xb, wt1, q1h, q1l);
            conv2_mfma<1><<<dim3(16, 16, 2), blk, 0, stream>>>(q1h, q1l, wA2h, wA2l, q2h, q2l);
            conv3_mfma<1><<<dim3(16, 16, 2), blk, 0, stream>>>(q2h, q2l, wA3h, wA3l,
                                                               xb, pacw, pacb, outb);
        }
    }
}